// Round 3
// baseline (7435.930 us; speedup 1.0000x reference)
//
#include <hip/hip_runtime.h>
#include <hip/hip_bf16.h>
#include <stdint.h>
#include <stddef.h>

// Problem dims
#define B_    64
#define L_    64
#define T_    15
#define V_    32000
#define E_    512
#define H_    1024
#define ENC_  1024
#define ATT_  512
#define S_    128

// Output layout (f32 elements): logits | dec_log_probs | preds | attns
#define DEC_OFF  30720000   // B*T*V
#define PRED_OFF 30720960   // + B*T
#define ATT_OFF  30721920   // + B*T

// ---------------------------------------------------------------------------
// Skinny GEMM, scalar-W variant: CT[n][m] = sum_k W[n][k] * A[k][m]
//   No LDS, no barriers. W addresses are wave-uniform (readfirstlane-hoisted)
//   so the compiler scalarizes W reads to s_load -> SGPRs, consumed directly
//   as the SGPR operand of v_fmac_f32. A is per-lane (lane = m), double-
//   buffered in registers; the next chunk's A-loads are issued before the
//   FMA block that hides them. Per 32-k chunk / wave: JT*32 FMA + 32 A-loads
//   + JT*8 scalar loads. Scalar pipe runs concurrently with VALU.
//   Wave wid = blockIdx.x*4 + wv owns rows [wid*JT, wid*JT+JT).
//   K split across blockIdx.z chunks of KB (partials written per z).
// AMODE: 0 = A is f32 [K][64] at AT
//        1 = A is the gathered x vector: emb|style|ctx  (gi GEMM)
//        2 = A is f32 [M,K] row-major at Af (enc_output -> keys_proj)
// OUTMODE: 0 = write f32 Cout[z*zstride + n*c_sn + m*c_sm] (+bias if given)
//          1 = W2 path: fused bias + f32 logits write + online max/sum/argmax
//              partials (pmax/psum/pidx indexed [wid*64 + lane])
// ---------------------------------------------------------------------------
template<int AMODE, int OUTMODE, int JT>
__global__ __launch_bounds__(256) void gemm_s(
    const float* __restrict__ W, int K, int KB,
    const float* __restrict__ AT,
    const float* __restrict__ Af,
    const float* __restrict__ stab,
    const int* __restrict__ previ,
    const int* __restrict__ styles,
    const float* __restrict__ chT,
    const float* __restrict__ bias,
    float* __restrict__ Cout, size_t zstride, int c_sn, int c_sm,
    float* __restrict__ out2, int t,
    float* __restrict__ pmax, float* __restrict__ psum, int* __restrict__ pidx)
{
  const int tid  = threadIdx.x;
  const int lane = tid & 63;
  const int wv   = __builtin_amdgcn_readfirstlane(tid >> 6);
  const int wid  = blockIdx.x * 4 + wv;
  const int n0   = wid * JT;
  const int m0   = blockIdx.y * 64;
  const int kb0  = blockIdx.z * KB;

  long erow = 0, srow = 0;
  if (AMODE == 1) {
    int pv = previ[lane];
    if (pv < 0 || pv >= V_) pv = 0;       // defensive: never fault on a bad argmax
    erow = (long)pv * E_;
    srow = (long)styles[lane] * S_;
  }

  auto xfetch = [&](int k) -> float {
    if (k < E_)            return Af[erow + k];
    else if (k < E_ + S_)  return stab[srow + (k - E_)];
    else                   return chT[(size_t)(k - (E_ + S_)) * 64 + lane];
  };

  auto loadA = [&](int kc, float* a) {
    if constexpr (AMODE == 0) {
#pragma unroll
      for (int kk = 0; kk < 32; ++kk)
        a[kk] = AT[(size_t)(kc + kk) * 64 + lane];
    } else if constexpr (AMODE == 2) {
      const float4* ar = (const float4*)(Af + (size_t)(m0 + lane) * K + kc);
#pragma unroll
      for (int kk = 0; kk < 8; ++kk) {
        float4 u = ar[kk];
        a[4 * kk + 0] = u.x; a[4 * kk + 1] = u.y;
        a[4 * kk + 2] = u.z; a[4 * kk + 3] = u.w;
      }
    } else {
#pragma unroll
      for (int kk = 0; kk < 32; ++kk) a[kk] = xfetch(kc + kk);
    }
  };

  float acc[JT];
#pragma unroll
  for (int j = 0; j < JT; ++j) acc[j] = 0.f;

  auto rowsFMA = [&](int kc, const float* a) {
    const float* wp = W + (size_t)n0 * K + kc;   // wave-uniform base
#pragma unroll
    for (int j = 0; j < JT; ++j) {
      const float4* wr = (const float4*)(wp + (size_t)j * K);
#pragma unroll
      for (int k4 = 0; k4 < 8; ++k4) {
        float4 w = wr[k4];                       // uniform -> s_load
        acc[j] = fmaf(w.x, a[4 * k4 + 0], acc[j]);
        acc[j] = fmaf(w.y, a[4 * k4 + 1], acc[j]);
        acc[j] = fmaf(w.z, a[4 * k4 + 2], acc[j]);
        acc[j] = fmaf(w.w, a[4 * k4 + 3], acc[j]);
      }
    }
  };

  // Main loop: 64 k per iteration, A register-double-buffered (static idx only)
  float aA[32], aB[32];
  loadA(kb0, aA);
  for (int kc = kb0; kc < kb0 + KB; kc += 64) {
    loadA(kc + 32, aB);
    rowsFMA(kc, aA);
    if (kc + 64 < kb0 + KB) loadA(kc + 64, aA);
    rowsFMA(kc + 32, aB);
  }

  if (OUTMODE == 0) {
    float* cb = Cout + (size_t)blockIdx.z * zstride;
#pragma unroll
    for (int j = 0; j < JT; ++j) {
      float c = acc[j];
      if (bias) c += bias[n0 + j];
      cb[(size_t)(n0 + j) * c_sn + (size_t)(m0 + lane) * c_sm] = c;
    }
  } else {
    float vmax = -__builtin_inff(); float s = 0.f; int vidx = 0x7fffffff;
    float ob[JT];
#pragma unroll
    for (int j = 0; j < JT; ++j) {
      float c = acc[j] + bias[n0 + j];
      ob[j] = c;
      if (c > vmax) { s = s * __expf(vmax - c) + 1.f; vmax = c; vidx = n0 + j; }
      else          { s += __expf(c - vmax); }
    }
    float* op = out2 + (size_t)lane * (T_ * V_) + (size_t)t * V_ + n0;
#pragma unroll
    for (int jq = 0; jq < JT / 4; ++jq) {
      float4 q;
      q.x = ob[4 * jq + 0]; q.y = ob[4 * jq + 1];
      q.z = ob[4 * jq + 2]; q.w = ob[4 * jq + 3];
      ((float4*)op)[jq] = q;
    }
    int pb = wid * 64 + lane;
    pmax[pb] = vmax; psum[pb] = s; pidx[pb] = vidx;
  }
}

// ---------------------------------------------------------------------------
__global__ __launch_bounds__(256) void gru_combine(
    const float* __restrict__ gip, const float* __restrict__ ghp,
    const float* __restrict__ b_ih, const float* __restrict__ b_hh,
    float* __restrict__ chT)
{
  int tgl = blockIdx.x * 256 + threadIdx.x;   // 64*1024
  int b = tgl & 63; int i = tgl >> 6;
  float ir = b_ih[i], iz = b_ih[H_ + i], in_ = b_ih[2 * H_ + i];
  float hr = b_hh[i], hz = b_hh[H_ + i], hn  = b_hh[2 * H_ + i];
  for (int kz = 0; kz < 13; ++kz) {
    const float* p = gip + (size_t)kz * (3 * H_ * 64);
    ir  += p[(size_t)i * 64 + b];
    iz  += p[(size_t)(H_ + i) * 64 + b];
    in_ += p[(size_t)(2 * H_ + i) * 64 + b];
  }
  for (int kz = 0; kz < 8; ++kz) {
    const float* p = ghp + (size_t)kz * (3 * H_ * 64);
    hr += p[(size_t)i * 64 + b];
    hz += p[(size_t)(H_ + i) * 64 + b];
    hn += p[(size_t)(2 * H_ + i) * 64 + b];
  }
  float r = 1.f / (1.f + expf(-(ir + hr)));
  float z = 1.f / (1.f + expf(-(iz + hz)));
  float n = tanhf(in_ + r * hn);
  float h = chT[(size_t)(H_ + i) * 64 + b];
  chT[(size_t)(H_ + i) * 64 + b] = (1.f - z) * n + z * h;
}

__global__ __launch_bounds__(256) void o_combine(
    const float* __restrict__ op, const float* __restrict__ b1,
    float* __restrict__ oT)
{
  int tgl = blockIdx.x * 256 + threadIdx.x;   // 64*1024
  int b = tgl & 63; int i = tgl >> 6;
  float v = b1[i];
  for (int kz = 0; kz < 8; ++kz) v += op[(size_t)kz * (H_ * 64) + (size_t)i * 64 + b];
  v = (v >= 0.f) ? v : 0.1f * v;   // LeakyReLU(0.1)
  oT[(size_t)i * 64 + b] = v;
}

// ---------------------------------------------------------------------------
// Attention, split for parallelism:
//   1. q partials via gemm_s<0,0,4> (Wq, A = hT), 8 K-splits -> qp[z][b][a]
//   2. energy_kernel: one wave per (b,l) -> 4096 waves
//   3. softmax_ctx: 4 blocks per b; redundant tiny softmax, coalesced ctx
// ---------------------------------------------------------------------------
__global__ __launch_bounds__(256) void energy_kernel(
    const float* __restrict__ qp,     // [8][64][512] q partials
    const float* __restrict__ kp,     // [B*L][512]
    const float* __restrict__ cov,    // [B][L]
    const float* __restrict__ Wc, const float* __restrict__ Wo,
    const float* __restrict__ bq,
    const int* __restrict__ enc_len,
    float* __restrict__ en)           // [B][L] masked energies
{
  const int lane = threadIdx.x & 63;
  const int wv   = threadIdx.x >> 6;
  const int w    = blockIdx.x * 4 + wv;   // 0..4095
  const int b    = w >> 6;
  const int l    = w & 63;

  const float cv = cov[b * L_ + l];
  const float* kpr = kp + ((size_t)b * L_ + l) * ATT_;
  const float* qb  = qp + (size_t)b * ATT_;

  float e = 0.f;
#pragma unroll
  for (int i = 0; i < 8; ++i) {
    int a = lane + i * 64;
    float q = bq[a];
#pragma unroll
    for (int z = 0; z < 8; ++z) q += qb[(size_t)z * (B_ * ATT_) + a];
    e += tanhf(q + kpr[a] + cv * Wc[a]) * Wo[a];
  }
#pragma unroll
  for (int off = 32; off > 0; off >>= 1) e += __shfl_down(e, off);
  if (lane == 0) en[b * L_ + l] = (l < enc_len[b]) ? e : -1e10f;
}

__global__ __launch_bounds__(256) void softmax_ctx(
    const float* __restrict__ en,     // [B][L] masked energies
    float* __restrict__ cov,
    float* __restrict__ out_attn,
    const float* __restrict__ enc,
    float* __restrict__ chT, int t)
{
  __shared__ float a_s[L_];
  const int b     = blockIdx.x >> 2;
  const int chunk = blockIdx.x & 3;
  const int tid   = threadIdx.x;

  if (tid < L_) {
    float v = en[b * L_ + tid];
    float mx = v;
#pragma unroll
    for (int off = 32; off > 0; off >>= 1) mx = fmaxf(mx, __shfl_xor(mx, off));
    float ex = expf(v - mx);
    float sm = ex;
#pragma unroll
    for (int off = 32; off > 0; off >>= 1) sm += __shfl_xor(sm, off);
    float at = ex / sm;
    a_s[tid] = at;
    if (chunk == 0) {
      cov[b * L_ + tid] += at;
      out_attn[((size_t)b * T_ + t) * L_ + tid] = at;
    }
  }
  __syncthreads();

  const int d = chunk * 256 + tid;
  const float* ep = enc + ((size_t)b * L_) * ENC_ + d;
  float acc0 = 0.f, acc1 = 0.f, acc2 = 0.f, acc3 = 0.f;
#pragma unroll
  for (int l = 0; l < L_; l += 4) {
    acc0 = fmaf(a_s[l + 0], ep[(size_t)(l + 0) * ENC_], acc0);
    acc1 = fmaf(a_s[l + 1], ep[(size_t)(l + 1) * ENC_], acc1);
    acc2 = fmaf(a_s[l + 2], ep[(size_t)(l + 2) * ENC_], acc2);
    acc3 = fmaf(a_s[l + 3], ep[(size_t)(l + 3) * ENC_], acc3);
  }
  chT[(size_t)d * 64 + b] = acc0 + acc1 + acc2 + acc3;   // ctx rows [0,1024)
}

// ---------------------------------------------------------------------------
__global__ __launch_bounds__(256) void lse_final(
    const float* __restrict__ pmax, const float* __restrict__ psum,
    const int* __restrict__ pidx,
    float* __restrict__ out, int* __restrict__ previ, int t, int NP)
{
  __shared__ float smx[4]; __shared__ int sid[4]; __shared__ float ssm[4];
  int b = blockIdx.x; int tid = threadIdx.x;
  int lane = tid & 63; int wv = tid >> 6;

  float vmax = -__builtin_inff(); int vidx = 0x7fffffff;
  for (int p = tid; p < NP; p += 256) {
    float v = pmax[(size_t)p * 64 + b]; int i = pidx[(size_t)p * 64 + b];
    if (v > vmax || (v == vmax && i < vidx)) { vmax = v; vidx = i; }
  }
#pragma unroll
  for (int off = 32; off > 0; off >>= 1) {
    float ov = __shfl_xor(vmax, off); int oi = __shfl_xor(vidx, off);
    if (ov > vmax || (ov == vmax && oi < vidx)) { vmax = ov; vidx = oi; }
  }
  if (lane == 0) { smx[wv] = vmax; sid[wv] = vidx; }
  __syncthreads();
  float gmax = smx[0]; int gidx = sid[0];
#pragma unroll
  for (int w = 1; w < 4; ++w) {
    float v = smx[w]; int i = sid[w];
    if (v > gmax || (v == gmax && i < gidx)) { gmax = v; gidx = i; }
  }

  float s = 0.f;
  for (int p = tid; p < NP; p += 256)
    s += psum[(size_t)p * 64 + b] * __expf(pmax[(size_t)p * 64 + b] - gmax);
#pragma unroll
  for (int off = 32; off > 0; off >>= 1) s += __shfl_xor(s, off);
  if (lane == 0) ssm[wv] = s;
  __syncthreads();
  if (tid == 0) {
    s = ssm[0] + ssm[1] + ssm[2] + ssm[3];
    if (gidx < 0 || gidx >= V_) gidx = 0;           // defensive clamp
    out[DEC_OFF  + b * T_ + t] = -logf(s);          // logit[pred]=max -> max-LSE
    out[PRED_OFF + b * T_ + t] = (float)gidx;       // exact: gidx < 2^24
    previ[b] = gidx;
  }
}

__global__ __launch_bounds__(256) void init_state(float* chT, float* cov, int* previ)
{
  int tgl = blockIdx.x * 256 + threadIdx.x;
  if (tgl < 2048 * 64) chT[tgl] = 0.f;
  else if (tgl < 2048 * 64 + 64 * 64) cov[tgl - 2048 * 64] = 0.f;
  else if (tgl < 2048 * 64 + 64 * 64 + 64) previ[tgl - (2048 * 64 + 64 * 64)] = 1; // BOS
}

// ---------------------------------------------------------------------------
extern "C" void kernel_launch(void* const* d_in, const int* in_sizes, int n_in,
                              void* d_out, int out_size, void* d_ws, size_t ws_size,
                              hipStream_t stream)
{
  const float* enc     = (const float*)d_in[0];
  const int*   enc_len = (const int*)d_in[1];
  const int*   styles  = (const int*)d_in[2];
  const float* emb     = (const float*)d_in[3];
  const float* stab    = (const float*)d_in[4];
  const float* Wq      = (const float*)d_in[5];
  const float* bq      = (const float*)d_in[6];
  const float* Wk      = (const float*)d_in[7];
  const float* Wc      = (const float*)d_in[8];
  const float* Wo      = (const float*)d_in[9];
  const float* W_ih    = (const float*)d_in[10];
  const float* b_ih    = (const float*)d_in[11];
  const float* W_hh    = (const float*)d_in[12];
  const float* b_hh    = (const float*)d_in[13];
  const float* W1      = (const float*)d_in[14];
  const float* b1      = (const float*)d_in[15];
  const float* W2      = (const float*)d_in[16];
  const float* b2      = (const float*)d_in[17];
  float* out = (float*)d_out;

  char* ws = (char*)d_ws;
  float* kp   = (float*)(ws + 0);          // [4096][512] f32  keys_proj[m][a]
  float* chT  = (float*)(ws + 8388608);    // [2048][64]  ctx rows 0..1023 | h rows 1024..2047
  float* cov  = (float*)(ws + 8912896);    // [64][64]
  float* gi_p = (float*)(ws + 8929280);    // [13][3072][64]
  float* gh_p = (float*)(ws + 19152896);   // [8][3072][64]
  float* o_p  = (float*)(ws + 25444352);   // [8][1024][64]
  float* oT   = (float*)(ws + 27541504);   // [1024][64]
  int*   prev = (int*)  (ws + 29339648);   // [64]

  // Aliased into gi_p's region: gi_p is consumed by gru_combine before the
  // q GEMM writes qp, and qp/en are consumed (energy/softmax_ctx) before the
  // next step's gi GEMM rewrites gi_p. Lifetimes are disjoint within a step.
  float* qp   = gi_p;                      // [8][64][512] q partials [z][b][a]
  float* en   = gi_p + 8 * B_ * ATT_;      // [64][64] masked energies

  // Aliased into gh_p's region (dead after gru_combine, rewritten next step
  // AFTER lse_final consumed these): W2 LSE/argmax partials, 4000 slots.
  float* pmax = gh_p;                      // [4000][64]
  float* psum = gh_p + 4000 * 64;          // [4000][64]
  int*   pidx = (int*)(gh_p + 2 * 4000 * 64); // [4000][64]

  init_state<<<529, 256, 0, stream>>>(chT, cov, prev);

  // keys_proj (hoisted): kp[b*64+l][a] = enc[b,l,:] . Wk[a,:]
  gemm_s<2, 0, 8><<<dim3(16, 64, 1), 256, 0, stream>>>(
      Wk, ENC_, ENC_,
      nullptr, enc, nullptr, nullptr, nullptr, nullptr, nullptr,
      kp, 0, /*c_sn=*/1, /*c_sm=*/ATT_, nullptr, 0, nullptr, nullptr, nullptr);

  for (int t = 0; t < T_; ++t) {
    // gi = x @ W_ih^T (x gathered: emb[prev] | style | ctx), K=1664, 13 K-splits
    gemm_s<1, 0, 8><<<dim3(96, 1, 13), 256, 0, stream>>>(
        W_ih, 1664, 128,
        nullptr, emb, stab, prev, styles, chT, nullptr,
        gi_p, (size_t)3 * H_ * 64, 64, 1, nullptr, 0, nullptr, nullptr, nullptr);
    // gh = h @ W_hh^T, K=1024, 8 K-splits
    gemm_s<0, 0, 4><<<dim3(192, 1, 8), 256, 0, stream>>>(
        W_hh, H_, 128,
        chT + (size_t)H_ * 64, nullptr, nullptr, nullptr, nullptr, nullptr, nullptr,
        gh_p, (size_t)3 * H_ * 64, 64, 1, nullptr, 0, nullptr, nullptr, nullptr);
    gru_combine<<<256, 256, 0, stream>>>(gi_p, gh_p, b_ih, b_hh, chT);

    // q = h @ Wq^T (no bias here; bq added in energy_kernel), 8 K-splits
    // qp[z][b][a]: zstride = B*ATT, c_sn (n=a) = 1, c_sm (m=b) = ATT
    gemm_s<0, 0, 4><<<dim3(32, 1, 8), 256, 0, stream>>>(
        Wq, H_, 128,
        chT + (size_t)H_ * 64, nullptr, nullptr, nullptr, nullptr, nullptr, nullptr,
        qp, (size_t)B_ * ATT_, /*c_sn=*/1, /*c_sm=*/ATT_,
        nullptr, 0, nullptr, nullptr, nullptr);
    // energies: one wave per (b,l) -> 4096 waves / 1024 blocks
    energy_kernel<<<1024, 256, 0, stream>>>(qp, kp, cov, Wc, Wo, bq, enc_len, en);
    // softmax + cov update + attn out + ctx: 4 blocks per b
    softmax_ctx<<<256, 256, 0, stream>>>(en, cov, out + ATT_OFF, enc, chT, t);

    // o_pre = [ctx|h] @ W1^T, K=2048, 8 K-splits
    gemm_s<0, 0, 4><<<dim3(64, 1, 8), 256, 0, stream>>>(
        W1, 2 * H_, 256,
        chT, nullptr, nullptr, nullptr, nullptr, nullptr, nullptr,
        o_p, (size_t)H_ * 64, 64, 1, nullptr, 0, nullptr, nullptr, nullptr);
    o_combine<<<256, 256, 0, stream>>>(o_p, b1, oT);
    // logits = o @ W2^T + b2 : fused f32 logits out + online LSE/argmax partials
    gemm_s<0, 1, 8><<<dim3(1000, 1, 1), 256, 0, stream>>>(
        W2, H_, H_,
        oT, nullptr, nullptr, nullptr, nullptr, nullptr, b2,
        nullptr, 0, 0, 0, out, t, pmax, psum, pidx);
    lse_final<<<64, 256, 0, stream>>>(pmax, psum, pidx, out, prev, t, 4000);
  }
}

// Round 4
// 3389.428 us; speedup vs baseline: 2.1939x; 2.1939x over previous
//
#include <hip/hip_runtime.h>
#include <hip/hip_bf16.h>
#include <stdint.h>
#include <stddef.h>

// Problem dims
#define B_    64
#define L_    64
#define T_    15
#define V_    32000
#define E_    512
#define H_    1024
#define ENC_  1024
#define ATT_  512
#define S_    128

// Output layout (f32 elements): logits | dec_log_probs | preds | attns
#define DEC_OFF  30720000   // B*T*V
#define PRED_OFF 30720960   // + B*T
#define ATT_OFF  30721920   // + B*T

// ---------------------------------------------------------------------------
// Generic skinny GEMM, "variant B" (round-2 proven): CT[n][m] = W[n][k]·A[k][m]
//   Block: 256 thr = 4 waves. Block tile: NT n-rows x 64 m(batch). lane = m.
//   Wave wv handles n = n0 + wv*JT + j -> acc[JT] per lane.
//   K split across blockIdx.z chunks of KB (partials written per z).
//   Register-double-buffered W staging (A-loads issued before the prefetch).
// AMODE: 0 = A is f32 [K][64] at AT
//        1 = A is the gathered x vector: emb|style|ctx  (gi GEMM)
//        2 = A is f32 [M,K] row-major at Af (enc_output -> keys_proj)
// ---------------------------------------------------------------------------
template<int AMODE, int NT>
__global__ __launch_bounds__(256) void gemm_b(
    const float* __restrict__ W, int N, int K, int KB,
    const float* __restrict__ AT,
    const float* __restrict__ Af,
    const float* __restrict__ stab,
    const int* __restrict__ previ,
    const int* __restrict__ styles,
    const float* __restrict__ chT,
    const float* __restrict__ bias,
    float* __restrict__ Cout, size_t zstride, int c_sn, int c_sm)
{
  constexpr int JT  = NT / 4;   // rows per wave
  constexpr int WLD = NT / 32;  // float4 stage loads per thread
  __shared__ float Ws[NT * 36];
  const int tid  = threadIdx.x;
  const int lane = tid & 63;
  const int wv   = tid >> 6;
  const int n0   = blockIdx.x * NT;
  const int m0   = blockIdx.y * 64;
  const int kb0  = blockIdx.z * KB;

  long erow = 0, srow = 0;
  if (AMODE == 1) {
    int pv = previ[lane];
    if (pv < 0 || pv >= V_) pv = 0;       // defensive: never fault on a bad argmax
    erow = (long)pv * E_;
    srow = (long)styles[lane] * S_;
  }

  auto xfetch = [&](int k) -> float {
    if (k < E_)            return Af[erow + k];
    else if (k < E_ + S_)  return stab[srow + (k - E_)];
    else                   return chT[(size_t)(k - (E_ + S_)) * 64 + lane];
  };

  auto ldW = [&](int kc, float4* u) {
    if constexpr (NT == 64) {
      int n = tid >> 2, k8 = (tid & 3) * 8;
      const float4* wp = (const float4*)(W + (size_t)(n0 + n) * K + kc + k8);
      u[0] = wp[0]; u[1] = wp[1];
    } else {
      int n = tid >> 3, k4 = (tid & 7) * 4;
      const float4* wp = (const float4*)(W + (size_t)(n0 + n) * K + kc + k4);
      u[0] = wp[0];
    }
  };
  auto stW = [&](const float4* u) {
    if constexpr (NT == 64) {
      int n = tid >> 2, k8 = (tid & 3) * 8;
      float* ds = &Ws[n * 36 + k8];
      ds[0] = u[0].x; ds[1] = u[0].y; ds[2] = u[0].z; ds[3] = u[0].w;
      ds[4] = u[1].x; ds[5] = u[1].y; ds[6] = u[1].z; ds[7] = u[1].w;
    } else {
      int n = tid >> 3, k4 = (tid & 7) * 4;
      float* ds = &Ws[n * 36 + k4];
      ds[0] = u[0].x; ds[1] = u[0].y; ds[2] = u[0].z; ds[3] = u[0].w;
    }
  };

  float acc[JT];
#pragma unroll
  for (int j = 0; j < JT; ++j) acc[j] = 0.f;

  float4 cu[WLD], nu[WLD];
  ldW(kb0, cu);

  for (int kc = kb0; kc < kb0 + KB; kc += 32) {
    stW(cu);
    __syncthreads();

    // A chunk into registers first (issue order matters: waiting on these
    // must not force the W-prefetch below to complete).
    float a[32];
    if constexpr (AMODE == 0) {
#pragma unroll
      for (int kk = 0; kk < 32; ++kk)
        a[kk] = AT[(size_t)(kc + kk) * 64 + lane];
    } else if constexpr (AMODE == 2) {
      const float4* ar = (const float4*)(Af + (size_t)(m0 + lane) * K + kc);
#pragma unroll
      for (int kk = 0; kk < 8; ++kk) {
        float4 u = ar[kk];
        a[4 * kk] = u.x; a[4 * kk + 1] = u.y; a[4 * kk + 2] = u.z; a[4 * kk + 3] = u.w;
      }
    } else {
#pragma unroll
      for (int kk = 0; kk < 32; ++kk) a[kk] = xfetch(kc + kk);
    }

    // Prefetch next W chunk (in flight during compute)
    if (kc + 32 < kb0 + KB) ldW(kc + 32, nu);

    const float* wr0 = &Ws[(wv * JT) * 36];
#pragma unroll
    for (int k = 0; k < 32; k += 4) {
#pragma unroll
      for (int j = 0; j < JT; ++j) {
        float4 w = *(const float4*)(wr0 + j * 36 + k);
        acc[j] = fmaf(w.x, a[k + 0], acc[j]);
        acc[j] = fmaf(w.y, a[k + 1], acc[j]);
        acc[j] = fmaf(w.z, a[k + 2], acc[j]);
        acc[j] = fmaf(w.w, a[k + 3], acc[j]);
      }
    }
    __syncthreads();
#pragma unroll
    for (int i = 0; i < WLD; ++i) cu[i] = nu[i];
  }

  const int nbase = n0 + wv * JT;
  float* cb = Cout + (size_t)blockIdx.z * zstride;
#pragma unroll
  for (int j = 0; j < JT; ++j) {
    float c = acc[j];
    if (bias) c += bias[nbase + j];
    cb[(size_t)(nbase + j) * c_sn + (size_t)(m0 + lane) * c_sm] = c;
  }
}

// ---------------------------------------------------------------------------
// Dedicated W2 logits GEMM: logits[m][n] = oT[k][m]·W2[n][k] + b2[n], fused
// online LSE/argmax partials. Designed to fix the LDS-broadcast bottleneck of
// gemm_b (each ds_read_b128 there fed only 4 FMAs, lane-broadcast):
//   lane = (q, m16): q = lane>>4 row-subgroup, m = (lane&15)*4 + mi (4 m/lane).
//   Each W ds_read_b128 (4 k of one row) feeds 16 FMAs (4 k x 4 m).
//   A (oT) staged in LDS per 32-k chunk (contiguous 8KB, coalesced load);
//   double-buffered LDS -> ONE barrier per chunk; global prefetch before
//   compute. Block tile: 64 n-rows x 64 m. Grid 500. K = 1024, no z-split.
// Epilogue: bias + float4 logits store + online max/sum/argmax per (lane, mi)
// over its 4 rows, butterfly-reduced across q (shfl_xor 16,32) -> one partial
// per (block, wave, m): 2000 slots.
// ---------------------------------------------------------------------------
__global__ __launch_bounds__(256) void logits_kernel(
    const float* __restrict__ W2, const float* __restrict__ oT,
    const float* __restrict__ b2,
    float* __restrict__ out2, int t,
    float* __restrict__ pmax, float* __restrict__ psum, int* __restrict__ pidx)
{
  __shared__ float Ws[2][64 * 36];
  __shared__ float As[2][32 * 64];
  const int tid  = threadIdx.x;
  const int lane = tid & 63;
  const int wv   = tid >> 6;
  const int q    = lane >> 4;        // row subgroup 0..3
  const int m4   = (lane & 15) * 4;  // m base (4 consecutive)
  const int n0   = blockIdx.x * 64;
  const int nb   = n0 + wv * 16 + q * 4;  // this lane's first row

  // staging mapping: W tile [64 rows][32 k], A tile [32 k][64 m] (contiguous)
  const int sr = tid >> 2;           // 0..63 row
  const int sk = (tid & 3) * 8;      // 0,8,16,24

  float4 wr0, wr1, ar0, ar1;
  auto ldG = [&](int kc) {
    const float4* wp = (const float4*)(W2 + (size_t)(n0 + sr) * H_ + kc + sk);
    wr0 = wp[0]; wr1 = wp[1];
    const float4* ap = (const float4*)(oT + (size_t)kc * 64);
    ar0 = ap[tid]; ar1 = ap[256 + tid];
  };
  auto stg = [&](int buf) {
    float* wd = &Ws[buf][sr * 36 + sk];
    wd[0] = wr0.x; wd[1] = wr0.y; wd[2] = wr0.z; wd[3] = wr0.w;
    wd[4] = wr1.x; wd[5] = wr1.y; wd[6] = wr1.z; wd[7] = wr1.w;
    float4* ad = (float4*)As[buf];
    ad[tid] = ar0; ad[256 + tid] = ar1;
  };

  float4 acc[4];
#pragma unroll
  for (int j = 0; j < 4; ++j) acc[j] = make_float4(0.f, 0.f, 0.f, 0.f);

  ldG(0); stg(0);
  __syncthreads();

  for (int it = 0; it < 32; ++it) {
    const int cur = it & 1;
    if (it < 31) ldG((it + 1) * 32);          // global prefetch in flight

    const float* wbase = &Ws[cur][(wv * 16 + q * 4) * 36];
    const float* abase = As[cur];
#pragma unroll
    for (int ks = 0; ks < 32; ks += 8) {
      float4 af[8];
#pragma unroll
      for (int kk = 0; kk < 8; ++kk)
        af[kk] = *(const float4*)(abase + (ks + kk) * 64 + m4);
#pragma unroll
      for (int j = 0; j < 4; ++j) {
        const float* wp = wbase + j * 36 + ks;
        float4 w0 = *(const float4*)(wp);
        float4 w1 = *(const float4*)(wp + 4);
#define FMA4(wv_, a_) \
        acc[j].x = fmaf(wv_, a_.x, acc[j].x); \
        acc[j].y = fmaf(wv_, a_.y, acc[j].y); \
        acc[j].z = fmaf(wv_, a_.z, acc[j].z); \
        acc[j].w = fmaf(wv_, a_.w, acc[j].w);
        FMA4(w0.x, af[0]) FMA4(w0.y, af[1]) FMA4(w0.z, af[2]) FMA4(w0.w, af[3])
        FMA4(w1.x, af[4]) FMA4(w1.y, af[5]) FMA4(w1.z, af[6]) FMA4(w1.w, af[7])
#undef FMA4
      }
    }
    if (it < 31) stg(cur ^ 1);   // waits on prefetch (vmcnt), writes other buf
    __syncthreads();
  }

  // ---- epilogue: bias, logits store, online LSE/argmax + q-butterfly ----
  float cj[4][4];   // [j: row][mi: m]
#pragma unroll
  for (int j = 0; j < 4; ++j) {
    float bj = b2[nb + j];
    cj[j][0] = acc[j].x + bj; cj[j][1] = acc[j].y + bj;
    cj[j][2] = acc[j].z + bj; cj[j][3] = acc[j].w + bj;
  }

#pragma unroll
  for (int mi = 0; mi < 4; ++mi) {
    float4 v = make_float4(cj[0][mi], cj[1][mi], cj[2][mi], cj[3][mi]);
    *(float4*)(out2 + (size_t)(m4 + mi) * (T_ * V_) + (size_t)t * V_ + nb) = v;
  }

  float vm[4], ss[4]; int vi[4];
#pragma unroll
  for (int mi = 0; mi < 4; ++mi) {
    float vmax = -__builtin_inff(); float s = 0.f; int vidx = 0x7fffffff;
#pragma unroll
    for (int j = 0; j < 4; ++j) {
      float c = cj[j][mi];
      if (c > vmax) { s = s * __expf(vmax - c) + 1.f; vmax = c; vidx = nb + j; }
      else          { s += __expf(c - vmax); }
    }
    vm[mi] = vmax; ss[mi] = s; vi[mi] = vidx;
  }
#pragma unroll
  for (int off = 16; off <= 32; off <<= 1) {
#pragma unroll
    for (int mi = 0; mi < 4; ++mi) {
      float om = __shfl_xor(vm[mi], off);
      float os = __shfl_xor(ss[mi], off);
      int   oi = __shfl_xor(vi[mi], off);
      float nm = fmaxf(vm[mi], om);
      ss[mi] = ss[mi] * __expf(vm[mi] - nm) + os * __expf(om - nm);
      vi[mi] = (om > vm[mi] || (om == vm[mi] && oi < vi[mi])) ? oi : vi[mi];
      vm[mi] = nm;
    }
  }
  if (q == 0) {
    int pb = blockIdx.x * 4 + wv;
#pragma unroll
    for (int mi = 0; mi < 4; ++mi) {
      pmax[(size_t)pb * 64 + m4 + mi] = vm[mi];
      psum[(size_t)pb * 64 + m4 + mi] = ss[mi];
      pidx[(size_t)pb * 64 + m4 + mi] = vi[mi];
    }
  }
}

// ---------------------------------------------------------------------------
__global__ __launch_bounds__(256) void gru_combine(
    const float* __restrict__ gip, const float* __restrict__ ghp,
    const float* __restrict__ b_ih, const float* __restrict__ b_hh,
    float* __restrict__ chT)
{
  int tgl = blockIdx.x * 256 + threadIdx.x;   // 64*1024
  int b = tgl & 63; int i = tgl >> 6;
  float ir = b_ih[i], iz = b_ih[H_ + i], in_ = b_ih[2 * H_ + i];
  float hr = b_hh[i], hz = b_hh[H_ + i], hn  = b_hh[2 * H_ + i];
  for (int kz = 0; kz < 13; ++kz) {
    const float* p = gip + (size_t)kz * (3 * H_ * 64);
    ir  += p[(size_t)i * 64 + b];
    iz  += p[(size_t)(H_ + i) * 64 + b];
    in_ += p[(size_t)(2 * H_ + i) * 64 + b];
  }
  for (int kz = 0; kz < 8; ++kz) {
    const float* p = ghp + (size_t)kz * (3 * H_ * 64);
    hr += p[(size_t)i * 64 + b];
    hz += p[(size_t)(H_ + i) * 64 + b];
    hn += p[(size_t)(2 * H_ + i) * 64 + b];
  }
  float r = 1.f / (1.f + expf(-(ir + hr)));
  float z = 1.f / (1.f + expf(-(iz + hz)));
  float n = tanhf(in_ + r * hn);
  float h = chT[(size_t)(H_ + i) * 64 + b];
  chT[(size_t)(H_ + i) * 64 + b] = (1.f - z) * n + z * h;
}

__global__ __launch_bounds__(256) void o_combine(
    const float* __restrict__ op, const float* __restrict__ b1,
    float* __restrict__ oT)
{
  int tgl = blockIdx.x * 256 + threadIdx.x;   // 64*1024
  int b = tgl & 63; int i = tgl >> 6;
  float v = b1[i];
  for (int kz = 0; kz < 8; ++kz) v += op[(size_t)kz * (H_ * 64) + (size_t)i * 64 + b];
  v = (v >= 0.f) ? v : 0.1f * v;   // LeakyReLU(0.1)
  oT[(size_t)i * 64 + b] = v;
}

// ---------------------------------------------------------------------------
// Attention, split for parallelism:
//   1. q partials via gemm_b<0,32> (Wq, A = hT), 8 K-splits -> qp[z][b][a]
//   2. energy_kernel: one wave per (b,l) -> 4096 waves
//   3. softmax_ctx: 4 blocks per b; redundant tiny softmax, coalesced ctx
// ---------------------------------------------------------------------------
__global__ __launch_bounds__(256) void energy_kernel(
    const float* __restrict__ qp,     // [8][64][512] q partials
    const float* __restrict__ kp,     // [B*L][512]
    const float* __restrict__ cov,    // [B][L]
    const float* __restrict__ Wc, const float* __restrict__ Wo,
    const float* __restrict__ bq,
    const int* __restrict__ enc_len,
    float* __restrict__ en)           // [B][L] masked energies
{
  const int lane = threadIdx.x & 63;
  const int wv   = threadIdx.x >> 6;
  const int w    = blockIdx.x * 4 + wv;   // 0..4095
  const int b    = w >> 6;
  const int l    = w & 63;

  const float cv = cov[b * L_ + l];
  const float* kpr = kp + ((size_t)b * L_ + l) * ATT_;
  const float* qb  = qp + (size_t)b * ATT_;

  float e = 0.f;
#pragma unroll
  for (int i = 0; i < 8; ++i) {
    int a = lane + i * 64;
    float q = bq[a];
#pragma unroll
    for (int z = 0; z < 8; ++z) q += qb[(size_t)z * (B_ * ATT_) + a];
    e += tanhf(q + kpr[a] + cv * Wc[a]) * Wo[a];
  }
#pragma unroll
  for (int off = 32; off > 0; off >>= 1) e += __shfl_down(e, off);
  if (lane == 0) en[b * L_ + l] = (l < enc_len[b]) ? e : -1e10f;
}

__global__ __launch_bounds__(256) void softmax_ctx(
    const float* __restrict__ en,     // [B][L] masked energies
    float* __restrict__ cov,
    float* __restrict__ out_attn,
    const float* __restrict__ enc,
    float* __restrict__ chT, int t)
{
  __shared__ float a_s[L_];
  const int b     = blockIdx.x >> 2;
  const int chunk = blockIdx.x & 3;
  const int tid   = threadIdx.x;

  if (tid < L_) {
    float v = en[b * L_ + tid];
    float mx = v;
#pragma unroll
    for (int off = 32; off > 0; off >>= 1) mx = fmaxf(mx, __shfl_xor(mx, off));
    float ex = expf(v - mx);
    float sm = ex;
#pragma unroll
    for (int off = 32; off > 0; off >>= 1) sm += __shfl_xor(sm, off);
    float at = ex / sm;
    a_s[tid] = at;
    if (chunk == 0) {
      cov[b * L_ + tid] += at;
      out_attn[((size_t)b * T_ + t) * L_ + tid] = at;
    }
  }
  __syncthreads();

  const int d = chunk * 256 + tid;
  const float* ep = enc + ((size_t)b * L_) * ENC_ + d;
  float acc0 = 0.f, acc1 = 0.f, acc2 = 0.f, acc3 = 0.f;
#pragma unroll
  for (int l = 0; l < L_; l += 4) {
    acc0 = fmaf(a_s[l + 0], ep[(size_t)(l + 0) * ENC_], acc0);
    acc1 = fmaf(a_s[l + 1], ep[(size_t)(l + 1) * ENC_], acc1);
    acc2 = fmaf(a_s[l + 2], ep[(size_t)(l + 2) * ENC_], acc2);
    acc3 = fmaf(a_s[l + 3], ep[(size_t)(l + 3) * ENC_], acc3);
  }
  chT[(size_t)d * 64 + b] = acc0 + acc1 + acc2 + acc3;   // ctx rows [0,1024)
}

// ---------------------------------------------------------------------------
__global__ __launch_bounds__(256) void lse_final(
    const float* __restrict__ pmax, const float* __restrict__ psum,
    const int* __restrict__ pidx,
    float* __restrict__ out, int* __restrict__ previ, int t, int NP)
{
  __shared__ float smx[4]; __shared__ int sid[4]; __shared__ float ssm[4];
  int b = blockIdx.x; int tid = threadIdx.x;
  int lane = tid & 63; int wv = tid >> 6;

  float vmax = -__builtin_inff(); int vidx = 0x7fffffff;
  for (int p = tid; p < NP; p += 256) {
    float v = pmax[(size_t)p * 64 + b]; int i = pidx[(size_t)p * 64 + b];
    if (v > vmax || (v == vmax && i < vidx)) { vmax = v; vidx = i; }
  }
#pragma unroll
  for (int off = 32; off > 0; off >>= 1) {
    float ov = __shfl_xor(vmax, off); int oi = __shfl_xor(vidx, off);
    if (ov > vmax || (ov == vmax && oi < vidx)) { vmax = ov; vidx = oi; }
  }
  if (lane == 0) { smx[wv] = vmax; sid[wv] = vidx; }
  __syncthreads();
  float gmax = smx[0]; int gidx = sid[0];
#pragma unroll
  for (int w = 1; w < 4; ++w) {
    float v = smx[w]; int i = sid[w];
    if (v > gmax || (v == gmax && i < gidx)) { gmax = v; gidx = i; }
  }

  float s = 0.f;
  for (int p = tid; p < NP; p += 256)
    s += psum[(size_t)p * 64 + b] * __expf(pmax[(size_t)p * 64 + b] - gmax);
#pragma unroll
  for (int off = 32; off > 0; off >>= 1) s += __shfl_xor(s, off);
  if (lane == 0) ssm[wv] = s;
  __syncthreads();
  if (tid == 0) {
    s = ssm[0] + ssm[1] + ssm[2] + ssm[3];
    if (gidx < 0 || gidx >= V_) gidx = 0;           // defensive clamp
    out[DEC_OFF  + b * T_ + t] = -logf(s);          // logit[pred]=max -> max-LSE
    out[PRED_OFF + b * T_ + t] = (float)gidx;       // exact: gidx < 2^24
    previ[b] = gidx;
  }
}

__global__ __launch_bounds__(256) void init_state(float* chT, float* cov, int* previ)
{
  int tgl = blockIdx.x * 256 + threadIdx.x;
  if (tgl < 2048 * 64) chT[tgl] = 0.f;
  else if (tgl < 2048 * 64 + 64 * 64) cov[tgl - 2048 * 64] = 0.f;
  else if (tgl < 2048 * 64 + 64 * 64 + 64) previ[tgl - (2048 * 64 + 64 * 64)] = 1; // BOS
}

// ---------------------------------------------------------------------------
extern "C" void kernel_launch(void* const* d_in, const int* in_sizes, int n_in,
                              void* d_out, int out_size, void* d_ws, size_t ws_size,
                              hipStream_t stream)
{
  const float* enc     = (const float*)d_in[0];
  const int*   enc_len = (const int*)d_in[1];
  const int*   styles  = (const int*)d_in[2];
  const float* emb     = (const float*)d_in[3];
  const float* stab    = (const float*)d_in[4];
  const float* Wq      = (const float*)d_in[5];
  const float* bq      = (const float*)d_in[6];
  const float* Wk      = (const float*)d_in[7];
  const float* Wc      = (const float*)d_in[8];
  const float* Wo      = (const float*)d_in[9];
  const float* W_ih    = (const float*)d_in[10];
  const float* b_ih    = (const float*)d_in[11];
  const float* W_hh    = (const float*)d_in[12];
  const float* b_hh    = (const float*)d_in[13];
  const float* W1      = (const float*)d_in[14];
  const float* b1      = (const float*)d_in[15];
  const float* W2      = (const float*)d_in[16];
  const float* b2      = (const float*)d_in[17];
  float* out = (float*)d_out;

  char* ws = (char*)d_ws;
  float* kp   = (float*)(ws + 0);          // [4096][512] f32  keys_proj[m][a]
  float* chT  = (float*)(ws + 8388608);    // [2048][64]  ctx rows 0..1023 | h rows 1024..2047
  float* cov  = (float*)(ws + 8912896);    // [64][64]
  float* gi_p = (float*)(ws + 8929280);    // [13][3072][64]
  float* gh_p = (float*)(ws + 19152896);   // [8][3072][64]
  float* o_p  = (float*)(ws + 25444352);   // [8][1024][64]
  float* oT   = (float*)(ws + 27541504);   // [1024][64]
  int*   prev = (int*)  (ws + 29339648);   // [64]

  // Aliased into gi_p's region: gi_p is consumed by gru_combine before the
  // q GEMM writes qp, and qp/en are consumed (energy/softmax_ctx) before the
  // next step's gi GEMM rewrites gi_p. Lifetimes are disjoint within a step.
  float* qp   = gi_p;                      // [8][64][512] q partials [z][b][a]
  float* en   = gi_p + 8 * B_ * ATT_;      // [64][64] masked energies

  // Aliased into gh_p's region (dead after gru_combine, rewritten next step
  // AFTER lse_final consumed these): W2 LSE/argmax partials, 2000 slots.
  float* pmax = gh_p;                      // [2000][64]
  float* psum = gh_p + 2000 * 64;          // [2000][64]
  int*   pidx = (int*)(gh_p + 2 * 2000 * 64); // [2000][64]

  init_state<<<529, 256, 0, stream>>>(chT, cov, prev);

  // keys_proj (hoisted): kp[b*64+l][a] = enc[b,l,:] . Wk[a,:]
  gemm_b<2, 64><<<dim3(8, 64, 1), 256, 0, stream>>>(
      Wk, ATT_, ENC_, ENC_,
      nullptr, enc, nullptr, nullptr, nullptr, nullptr, nullptr,
      kp, 0, /*c_sn=*/1, /*c_sm=*/ATT_);

  for (int t = 0; t < T_; ++t) {
    // gi = x @ W_ih^T (x gathered: emb[prev] | style | ctx), K=1664, 13 K-splits
    gemm_b<1, 32><<<dim3(96, 1, 13), 256, 0, stream>>>(
        W_ih, 3 * H_, 1664, 128,
        nullptr, emb, stab, prev, styles, chT, nullptr,
        gi_p, (size_t)3 * H_ * 64, 64, 1);
    // gh = h @ W_hh^T, K=1024, 8 K-splits
    gemm_b<0, 32><<<dim3(96, 1, 8), 256, 0, stream>>>(
        W_hh, 3 * H_, H_, 128,
        chT + (size_t)H_ * 64, nullptr, nullptr, nullptr, nullptr, nullptr, nullptr,
        gh_p, (size_t)3 * H_ * 64, 64, 1);
    gru_combine<<<256, 256, 0, stream>>>(gi_p, gh_p, b_ih, b_hh, chT);

    // q = h @ Wq^T (no bias here; bq added in energy_kernel), 8 K-splits
    // qp[z][b][a]: zstride = B*ATT, c_sn (n=a) = 1, c_sm (m=b) = ATT
    gemm_b<0, 32><<<dim3(16, 1, 8), 256, 0, stream>>>(
        Wq, ATT_, H_, 128,
        chT + (size_t)H_ * 64, nullptr, nullptr, nullptr, nullptr, nullptr, nullptr,
        qp, (size_t)B_ * ATT_, /*c_sn=*/1, /*c_sm=*/ATT_);
    // energies: one wave per (b,l) -> 4096 waves / 1024 blocks
    energy_kernel<<<1024, 256, 0, stream>>>(qp, kp, cov, Wc, Wo, bq, enc_len, en);
    // softmax + cov update + attn out + ctx: 4 blocks per b
    softmax_ctx<<<256, 256, 0, stream>>>(en, cov, out + ATT_OFF, enc, chT, t);

    // o_pre = [ctx|h] @ W1^T, K=2048, 8 K-splits
    gemm_b<0, 32><<<dim3(32, 1, 8), 256, 0, stream>>>(
        W1, H_, 2 * H_, 256,
        chT, nullptr, nullptr, nullptr, nullptr, nullptr, nullptr,
        o_p, (size_t)H_ * 64, 64, 1);
    o_combine<<<256, 256, 0, stream>>>(o_p, b1, oT);
    // logits = o @ W2^T + b2 : dedicated kernel, fused LSE/argmax partials
    logits_kernel<<<500, 256, 0, stream>>>(
        W2, oT, b2, out, t, pmax, psum, pidx);
    lse_final<<<64, 256, 0, stream>>>(pmax, psum, pidx, out, prev, t, 2000);
  }
}